// Round 4
// baseline (534.318 us; speedup 1.0000x reference)
//
#include <hip/hip_runtime.h>

typedef _Float16 h16;
typedef _Float16 h8 __attribute__((ext_vector_type(8)));
typedef float f4 __attribute__((ext_vector_type(4)));

#define NB 8192
#define NENC 4096
#define NH 128
#define NL 10
#define NT 12
#define PAD 138   // 69 dwords/row = 5 mod 32 -> max 2-way LDS bank aliasing

// ---- workspace layout (element offsets in halfs) ----
#define OFF_FCIN 0                    // packed fc_in_W  [128 x 4096] fp16
#define SZ_FCIN (128*4096)
#define OFF_W (OFF_FCIN + SZ_FCIN)    // packed Wih/Whh  [10][2][512 x 128] fp16
#define SZ_W (10*2*512*128)
#define OFF_ENC (OFF_W + SZ_W)        // enc (relu(fc_in)) [8192 x 128] fp16
#define SZ_ENC (8192*128)
// total ws usage: 5.77 MB

#define KLOG2 1.4426950408889634f

__device__ __forceinline__ f4 splat4(float v) { f4 r; r[0]=v; r[1]=v; r[2]=v; r[3]=v; return r; }
__device__ __forceinline__ h8 cvt8(float4 a, float4 b) {
  h8 r; r[0]=(h16)a.x; r[1]=(h16)a.y; r[2]=(h16)a.z; r[3]=(h16)a.w;
  r[4]=(h16)b.x; r[5]=(h16)b.y; r[6]=(h16)b.z; r[7]=(h16)b.w; return r;
}

// ---------------- prep: convert + pack fc_in_W and Wih/Whh only ----------------
__global__ __launch_bounds__(256) void prep(const float* __restrict__ fcinW,
                                            const float* __restrict__ Wih,
                                            const float* __restrict__ Whh,
                                            h16* __restrict__ wsh) {
  int idx = blockIdx.x * 256 + threadIdx.x;
  if (idx < 65536) {                          // fc_in_W [128][4096], Kd8=512
    int r = idx >> 9, k8 = idx & 511;
    const float* src = fcinW + r * 4096 + k8 * 8;
    h8 v = cvt8(*(const float4*)src, *(const float4*)(src + 4));
    *(h8*)(wsh + OFF_FCIN + (((r >> 4) * 512 + k8) * 128 + (r & 15) * 8)) = v;
  } else if (idx < 229376) {                  // Wih/Whh [10][512][128], Kd8=16
    int rel = idx - 65536;
    int l = rel >> 14, rr = rel & 16383;
    int ssel = rr >> 13, rk8 = rr & 8191;
    int r = rk8 >> 4, k8 = rk8 & 15;
    const float* src = (ssel ? Whh : Wih) + l * 65536 + r * 128 + k8 * 8;
    h8 v = cvt8(*(const float4*)src, *(const float4*)(src + 4));
    *(h8*)(wsh + OFF_W + (l * 2 + ssel) * 65536 +
           (((r >> 4) * 16 + k8) * 128 + (r & 15) * 8)) = v;
  }
}

// ---------------- fc_in GEMM: enc = relu(A @ W^T + b), fp16 out ----------------
__global__ __launch_bounds__(256) void kin(const float* __restrict__ A,
                                           const float* __restrict__ bvec,
                                           h16* __restrict__ wsh) {
  const h16* Wp = wsh + OFF_FCIN;
  h16* ench = wsh + OFF_ENC;
  int tid = threadIdx.x;
  int w = tid >> 6, lane = tid & 63, s = lane & 15, q = lane >> 4;
  int m0 = blockIdx.x * 16;
  int c0 = w * 32 + s, c1 = c0 + 16;
  f4 acc0 = splat4(bvec[c0]);
  f4 acc1 = splat4(bvec[c1]);
  const float* arow = A + (size_t)(m0 + s) * NENC;
  const h16* wp0 = Wp + (w * 2 + 0) * (512 * 128) + s * 8;
  const h16* wp1 = Wp + (w * 2 + 1) * (512 * 128) + s * 8;
#pragma unroll 4
  for (int kb = 0; kb < 128; ++kb) {
    int k0 = kb * 32 + q * 8;
    float4 x0 = *(const float4*)(arow + k0);
    float4 x1 = *(const float4*)(arow + k0 + 4);
    h8 af = cvt8(x0, x1);
    h8 b0 = *(const h8*)(wp0 + (kb * 4 + q) * 128);
    h8 b1 = *(const h8*)(wp1 + (kb * 4 + q) * 128);
    acc0 = __builtin_amdgcn_mfma_f32_16x16x32_f16(af, b0, acc0, 0, 0, 0);
    acc1 = __builtin_amdgcn_mfma_f32_16x16x32_f16(af, b1, acc1, 0, 0, 0);
  }
#pragma unroll
  for (int r = 0; r < 4; ++r) {
    int b = m0 + q * 4 + r;
    float v0 = acc0[r]; v0 = v0 > 0.f ? v0 : 0.f;
    float v1 = acc1[r]; v1 = v1 > 0.f ? v1 : 0.f;
    ench[(size_t)b * NH + c0] = (h16)v0;
    ench[(size_t)b * NH + c1] = (h16)v1;
  }
}

// ---------------- persistent LSTM + output head ----------------
// grid 256 = 1 WG/CU, block 512 = 8 waves (2/SIMD), 32 batch rows/WG.
// 13-slot LDS ring; one barrier per (l,t). Layer-0 x-gates (t-invariant)
// computed in-prologue from enc (32 MFMAs) and held in regs. Gate math fused:
// sig(i)*tanh(g) = (1-E2g)*rcp((1+Ei)(1+E2g)) -> 8 transcendentals/unit.
__global__ __launch_bounds__(512, 2) void lstm(h16* __restrict__ wsh,
                                               const float* __restrict__ bih,
                                               const float* __restrict__ bhh,
                                               const float* __restrict__ fcoutW,
                                               const float* __restrict__ fcoutb,
                                               float* __restrict__ out) {
  __shared__ h16 ring[13][32][PAD];   // 114816 B
  __shared__ float probst[32 * 26];
  int tid = threadIdx.x;
  int w = tid >> 6, lane = tid & 63, s = lane & 15, q = lane >> 4;
  int brow = blockIdx.x * 32;
  const h16* ench = wsh + OFF_ENC;
  h8 wx[4][4], wh[4][4];
  float c[2][4];

  // ---------- layer 0: gx = enc @ Wih0^T + b0 (t-invariant), in regs ----------
  f4 gx[4][2];
  {
    const h16* wih0 = wsh + OFF_W;
    const h16* whh0 = wih0 + 65536;
#pragma unroll
    for (int g = 0; g < 4; ++g) {
#pragma unroll
      for (int kt = 0; kt < 4; ++kt) {
        int off = (((g * 8 + w) * 16 + kt * 4 + q) * 128) + s * 8;
        wx[g][kt] = *(const h8*)(wih0 + off);
        wh[g][kt] = *(const h8*)(whh0 + off);
      }
      int bcol = g * 128 + w * 16 + s;
      float bb = bih[bcol] + bhh[bcol];
#pragma unroll
      for (int mt = 0; mt < 2; ++mt) gx[g][mt] = splat4(bb);
    }
#pragma unroll
    for (int mt = 0; mt < 2; ++mt) {
      h8 ax[4];
#pragma unroll
      for (int kt = 0; kt < 4; ++kt)
        ax[kt] = *(const h8*)(ench + (size_t)(brow + mt * 16 + s) * NH + kt * 32 + q * 8);
#pragma unroll
      for (int g = 0; g < 4; ++g)
#pragma unroll
        for (int kt = 0; kt < 4; ++kt)
          gx[g][mt] = __builtin_amdgcn_mfma_f32_16x16x32_f16(ax[kt], wx[g][kt], gx[g][mt], 0, 0, 0);
    }
  }
  // ---------- layer 0 time loop ----------
  {
#pragma unroll
    for (int mt = 0; mt < 2; ++mt)
#pragma unroll
      for (int r = 0; r < 4; ++r) c[mt][r] = 0.f;
    for (int t = 0; t < NT; ++t) {
      __syncthreads();
      int rw = t + 11; if (rw >= 13) rw -= 13;
      int rh = t + 10; if (rh >= 13) rh -= 13;
      f4 acc[4][2];
#pragma unroll
      for (int g = 0; g < 4; ++g)
#pragma unroll
        for (int mt = 0; mt < 2; ++mt) acc[g][mt] = gx[g][mt];
      if (t > 0) {
#pragma unroll
        for (int mt = 0; mt < 2; ++mt) {
          h8 ah[4];
#pragma unroll
          for (int kt = 0; kt < 4; ++kt)
            ah[kt] = *(const h8*)&ring[rh][mt * 16 + s][kt * 32 + q * 8];
#pragma unroll
          for (int g = 0; g < 4; ++g)
#pragma unroll
            for (int kt = 0; kt < 4; ++kt)
              acc[g][mt] = __builtin_amdgcn_mfma_f32_16x16x32_f16(ah[kt], wh[g][kt], acc[g][mt], 0, 0, 0);
        }
      }
#pragma unroll
      for (int mt = 0; mt < 2; ++mt)
#pragma unroll
        for (int r = 0; r < 4; ++r) {
          float iv = acc[0][mt][r], fv = acc[1][mt][r];
          float gv = fmaxf(acc[2][mt][r], -30.f), ov = acc[3][mt][r];
          float ui = __builtin_amdgcn_exp2f(-KLOG2 * iv);
          float ug = __builtin_amdgcn_exp2f(-2.f * KLOG2 * gv);
          float uf = __builtin_amdgcn_exp2f(-KLOG2 * fv);
          float ig = (1.f - ug) * __builtin_amdgcn_rcpf((1.f + ui) * (1.f + ug));
          float cc = c[mt][r] * __builtin_amdgcn_rcpf(1.f + uf) + ig;
          c[mt][r] = cc;
          float uo = __builtin_amdgcn_exp2f(-KLOG2 * ov);
          float uc = __builtin_amdgcn_exp2f(-2.f * KLOG2 * cc);
          float hv = (1.f - uc) * __builtin_amdgcn_rcpf((1.f + uo) * (1.f + uc));
          ring[rw][mt * 16 + q * 4 + r][w * 16 + s] = (h16)hv;
        }
    }
  }
  // ---------- layers 1..9 ----------
  for (int l = 1; l < NL; ++l) {
    const h16* wih = wsh + OFF_W + (size_t)(l * 2) * 65536;
    const h16* whh = wih + 65536;
    float bb[4];
#pragma unroll
    for (int g = 0; g < 4; ++g) {
#pragma unroll
      for (int kt = 0; kt < 4; ++kt) {
        int off = (((g * 8 + w) * 16 + kt * 4 + q) * 128) + s * 8;
        wx[g][kt] = *(const h8*)(wih + off);
        wh[g][kt] = *(const h8*)(whh + off);
      }
      int bcol = l * 512 + g * 128 + w * 16 + s;
      bb[g] = bih[bcol] + bhh[bcol];
    }
#pragma unroll
    for (int mt = 0; mt < 2; ++mt)
#pragma unroll
      for (int r = 0; r < 4; ++r) c[mt][r] = 0.f;
    int base = 12 - l;
    for (int t = 0; t < NT; ++t) {
      __syncthreads();
      int rr = t + base; if (rr >= 13) rr -= 13;
      int rw = rr - 1; if (rw < 0) rw += 13;
      int rh = rw - 1; if (rh < 0) rh += 13;
      f4 acc[4][2];
#pragma unroll
      for (int g = 0; g < 4; ++g)
#pragma unroll
        for (int mt = 0; mt < 2; ++mt) acc[g][mt] = splat4(bb[g]);
#pragma unroll
      for (int mt = 0; mt < 2; ++mt) {
        h8 ax[4];
#pragma unroll
        for (int kt = 0; kt < 4; ++kt)
          ax[kt] = *(const h8*)&ring[rr][mt * 16 + s][kt * 32 + q * 8];
#pragma unroll
        for (int g = 0; g < 4; ++g)
#pragma unroll
          for (int kt = 0; kt < 4; ++kt)
            acc[g][mt] = __builtin_amdgcn_mfma_f32_16x16x32_f16(ax[kt], wx[g][kt], acc[g][mt], 0, 0, 0);
      }
      if (t > 0) {
#pragma unroll
        for (int mt = 0; mt < 2; ++mt) {
          h8 ah[4];
#pragma unroll
          for (int kt = 0; kt < 4; ++kt)
            ah[kt] = *(const h8*)&ring[rh][mt * 16 + s][kt * 32 + q * 8];
#pragma unroll
          for (int g = 0; g < 4; ++g)
#pragma unroll
            for (int kt = 0; kt < 4; ++kt)
              acc[g][mt] = __builtin_amdgcn_mfma_f32_16x16x32_f16(ah[kt], wh[g][kt], acc[g][mt], 0, 0, 0);
        }
      }
#pragma unroll
      for (int mt = 0; mt < 2; ++mt)
#pragma unroll
        for (int r = 0; r < 4; ++r) {
          float iv = acc[0][mt][r], fv = acc[1][mt][r];
          float gv = fmaxf(acc[2][mt][r], -30.f), ov = acc[3][mt][r];
          float ui = __builtin_amdgcn_exp2f(-KLOG2 * iv);
          float ug = __builtin_amdgcn_exp2f(-2.f * KLOG2 * gv);
          float uf = __builtin_amdgcn_exp2f(-KLOG2 * fv);
          float ig = (1.f - ug) * __builtin_amdgcn_rcpf((1.f + ui) * (1.f + ug));
          float cc = c[mt][r] * __builtin_amdgcn_rcpf(1.f + uf) + ig;
          c[mt][r] = cc;
          float uo = __builtin_amdgcn_exp2f(-KLOG2 * ov);
          float uc = __builtin_amdgcn_exp2f(-2.f * KLOG2 * cc);
          float hv = (1.f - uc) * __builtin_amdgcn_rcpf((1.f + uo) * (1.f + uc));
          ring[rw][mt * 16 + q * 4 + r][w * 16 + s] = (h16)hv;
        }
    }
  }
  // ---- output head: layer-9 h(t) lives in ring slot (t+2)%13 ----
  __syncthreads();
  h8 wo[5][4];
  float bo[5];
#pragma unroll
  for (int nt = 0; nt < 5; ++nt) {
    int row = nt * 16 + s;
    bool ok = row < 75;
#pragma unroll
    for (int kt = 0; kt < 4; ++kt) {
      const float* p = ok ? (fcoutW + row * 128 + kt * 32 + q * 8) : fcoutW;
      float4 x0 = *(const float4*)p;
      float4 x1 = *(const float4*)(p + 4);
      h8 v = cvt8(x0, x1);
      if (!ok) for (int j = 0; j < 8; ++j) v[j] = (h16)0.f;
      wo[nt][kt] = v;
    }
    bo[nt] = ok ? fcoutb[row] : 0.f;
  }
  int tcount = (w < 4) ? 2 : 1;
  for (int ti = 0; ti < tcount; ++ti) {
    int t = w + ti * 8;
    int sl = t + 2; if (sl >= 13) sl -= 13;
#pragma unroll
    for (int mt = 0; mt < 2; ++mt) {
      h8 ax[4];
#pragma unroll
      for (int kt = 0; kt < 4; ++kt)
        ax[kt] = *(const h8*)&ring[sl][mt * 16 + s][kt * 32 + q * 8];
#pragma unroll
      for (int nt = 0; nt < 5; ++nt) {
        f4 a = splat4(bo[nt]);
#pragma unroll
        for (int kt = 0; kt < 4; ++kt)
          a = __builtin_amdgcn_mfma_f32_16x16x32_f16(ax[kt], wo[nt][kt], a, 0, 0, 0);
        int col = nt * 16 + s;
#pragma unroll
        for (int r = 0; r < 4; ++r) {
          int row = mt * 16 + q * 4 + r;
          int b = brow + row;
          float v = a[r];
          if (col < 50)
            out[(size_t)b * 600 + (col >> 1) * 24 + t * 2 + (col & 1)] = v;
          if (t == 11 && col >= 50 && col < 75)
            probst[row * 26 + (col - 50)] = v;
        }
      }
    }
  }
  __syncthreads();
  if (tid < 32) {
    float vals[25];
    float m = -1e30f;
#pragma unroll
    for (int j = 0; j < 25; ++j) { vals[j] = probst[tid * 26 + j]; m = vals[j] > m ? vals[j] : m; }
    float sum = 0.f;
#pragma unroll
    for (int j = 0; j < 25; ++j) {
      float e = __builtin_amdgcn_exp2f((vals[j] - m) * KLOG2);
      vals[j] = e; sum += e;
    }
    float rs = 1.0f / sum;
    size_t pb = (size_t)4915200 + (size_t)(brow + tid) * 25;
#pragma unroll
    for (int j = 0; j < 25; ++j) out[pb + j] = vals[j] * rs;
  }
}

extern "C" void kernel_launch(void* const* d_in, const int* in_sizes, int n_in,
                              void* d_out, int out_size, void* d_ws, size_t ws_size,
                              hipStream_t stream) {
  const float* backbone = (const float*)d_in[0];
  const float* fcinW    = (const float*)d_in[1];
  const float* fcinb    = (const float*)d_in[2];
  const float* Wih      = (const float*)d_in[3];
  const float* Whh      = (const float*)d_in[4];
  const float* bih      = (const float*)d_in[5];
  const float* bhh      = (const float*)d_in[6];
  const float* fcoutW   = (const float*)d_in[7];
  const float* fcoutb   = (const float*)d_in[8];
  h16* wsh = (h16*)d_ws;

  prep<<<896, 256, 0, stream>>>(fcinW, Wih, Whh, wsh);
  kin<<<512, 256, 0, stream>>>(backbone, fcinb, wsh);
  lstm<<<256, 512, 0, stream>>>(wsh, bih, bhh, fcoutW, fcoutb, (float*)d_out);
}